// Round 2
// baseline (6790.700 us; speedup 1.0000x reference)
//
#include <hip/hip_runtime.h>
#include <hip/hip_cooperative_groups.h>

typedef _Float16 half8  __attribute__((ext_vector_type(8)));
typedef _Float16 half4v __attribute__((ext_vector_type(4)));
typedef float    floatx4 __attribute__((ext_vector_type(4)));

#define B_ 32
#define S_ 512
#define I_ 1024
#define H_ 1024
#define M_TOT (B_ * S_)   // 16384

// ---------------------------------------------------------------------------
// fp32 -> fp16 conversion (vectorized, grid-stride), n multiple of 4
// ---------------------------------------------------------------------------
__global__ void cvt_f32_f16(const float* __restrict__ src, _Float16* __restrict__ dst, long n) {
  long i = ((long)blockIdx.x * blockDim.x + threadIdx.x) * 4;
  const long stride = (long)gridDim.x * blockDim.x * 4;
  for (; i < n; i += stride) {
    floatx4 v = *(const floatx4*)(src + i);
    half4v h = {(_Float16)v[0], (_Float16)v[1], (_Float16)v[2], (_Float16)v[3]};
    *(half4v*)(dst + i) = h;
  }
}

__global__ void bias_sum_kernel(const float* __restrict__ bihf, const float* __restrict__ bhhf,
                                const float* __restrict__ bihb, const float* __restrict__ bhhb,
                                float* __restrict__ bias) {
  int i = blockIdx.x * blockDim.x + threadIdx.x;
  if (i < H_) {
    bias[i]      = bihf[i] + bhhf[i];
    bias[H_ + i] = bihb[i] + bhhb[i];
  }
}

// ---------------------------------------------------------------------------
// GEMM: xp[dir][m][n] = sum_k x16[m][k] * W16[dir][n][k] + bias[dir][n]
// stored into out[m*2048 + dir*1024 + n]  (xp lives in d_out, updated in place
// later by the scan).
// 128x128 tile, BK=32, 4 waves (2x2), each wave 4x4 frags of 16x16x32 f16 MFMA.
// ---------------------------------------------------------------------------
__global__ void __launch_bounds__(256) gemm_xp_kernel(
    const _Float16* __restrict__ A,    // [16384][1024] x in f16
    const _Float16* __restrict__ W,    // [2][1024][1024] W_ih in f16
    const float*    __restrict__ bias, // [2][1024]
    float*          __restrict__ out)  // [16384][2048]
{
  __shared__ _Float16 alds[128 * 32];  // 8 KiB
  __shared__ _Float16 blds[128 * 32];  // 8 KiB

  const int dir = blockIdx.z;
  const int m0  = blockIdx.y * 128;
  const int n0  = blockIdx.x * 128;
  const int tid  = threadIdx.x;
  const int lane = tid & 63;
  const int wv   = tid >> 6;
  const int wm   = wv >> 1, wn = wv & 1;
  const int lrow = lane & 15;
  const int lkg  = lane >> 4;  // 0..3 -> k = lkg*8

  const _Float16* Wd = W + (long)dir * H_ * I_;

  floatx4 acc[4][4] = {};

  // staging: thread -> (row, 16-element segment)
  const int srow = tid >> 1;   // 0..127
  const int sseg = tid & 1;    // k offset 0 / 16

  for (int kt = 0; kt < 32; ++kt) {
    __syncthreads();  // protect LDS from previous iteration's readers
    {
      const _Float16* srcA = A  + (long)(m0 + srow) * I_ + kt * 32 + sseg * 16;
      const _Float16* srcB = Wd + (long)(n0 + srow) * I_ + kt * 32 + sseg * 16;
      half8 a0 = *(const half8*)(srcA);
      half8 a1 = *(const half8*)(srcA + 8);
      half8 b0 = *(const half8*)(srcB);
      half8 b1 = *(const half8*)(srcB + 8);
      const int sw = (srow & 7) << 4;
      const int base = srow * 64 + sseg * 32;
      *(half8*)((char*)alds + ((base     ) ^ sw)) = a0;
      *(half8*)((char*)alds + ((base + 16) ^ sw)) = a1;
      *(half8*)((char*)blds + ((base     ) ^ sw)) = b0;
      *(half8*)((char*)blds + ((base + 16) ^ sw)) = b1;
    }
    __syncthreads();

    half8 af[4], bf[4];
#pragma unroll
    for (int mt = 0; mt < 4; ++mt) {
      int r = wm * 64 + mt * 16 + lrow;
      int byte = (r * 64 + lkg * 16) ^ ((r & 7) << 4);
      af[mt] = *(const half8*)((const char*)alds + byte);
    }
#pragma unroll
    for (int ntt = 0; ntt < 4; ++ntt) {
      int r = wn * 64 + ntt * 16 + lrow;
      int byte = (r * 64 + lkg * 16) ^ ((r & 7) << 4);
      bf[ntt] = *(const half8*)((const char*)blds + byte);
    }
#pragma unroll
    for (int mt = 0; mt < 4; ++mt)
#pragma unroll
      for (int ntt = 0; ntt < 4; ++ntt)
        acc[mt][ntt] = __builtin_amdgcn_mfma_f32_16x16x32_f16(af[mt], bf[ntt], acc[mt][ntt], 0, 0, 0);
  }

  // epilogue: C/D layout col = lane&15 (n), row = (lane>>4)*4 + v (m)
#pragma unroll
  for (int mt = 0; mt < 4; ++mt) {
    int mrow = m0 + wm * 64 + mt * 16 + lkg * 4;
#pragma unroll
    for (int ntt = 0; ntt < 4; ++ntt) {
      int n = n0 + wn * 64 + ntt * 16 + lrow;
      float bv = bias[dir * H_ + n];
#pragma unroll
      for (int v = 0; v < 4; ++v) {
        out[(long)(mrow + v) * (2 * H_) + dir * H_ + n] = acc[mt][ntt][v] + bv;
      }
    }
  }
}

// ---------------------------------------------------------------------------
// Recurrent scan: 64 WGs (dir = wg>>5, 32 output rows each), cooperative.
// W_hh slice (32x1024) resident in LDS as f16 (XOR-swizzled).
// h double-buffered f16 in ws, broadcast via L2; one grid.sync per step.
// xp is read from d_out and overwritten in place with tanh output.
// ---------------------------------------------------------------------------
__global__ void __launch_bounds__(256) scan_kernel(
    const float* __restrict__ Whh_f,
    const float* __restrict__ Whh_b,
    float*       __restrict__ out,   // [B][S][2H]; holds xp on entry
    _Float16*    __restrict__ hbuf)  // [2 buf][2 dir][B][H]
{
  __shared__ _Float16 wlds[32 * 1024];  // 64 KiB

  const int w     = blockIdx.x;
  const int dir   = w >> 5;
  const int rows0 = (w & 31) * 32;
  const float* Whh = dir ? Whh_b : Whh_f;
  const int tid = threadIdx.x;

  // stage W_hh rows [rows0, rows0+32) as f16, swizzled: byte ^= (row&7)<<4
  for (int idx = tid; idx < 32 * 128; idx += 256) {
    const int r  = idx >> 7;    // 0..31
    const int kg = idx & 127;   // 16B group -> k = kg*8
    const float* src = Whh + (long)(rows0 + r) * H_ + kg * 8;
    floatx4 v0 = *(const floatx4*)(src);
    floatx4 v1 = *(const floatx4*)(src + 4);
    half8 h = {(_Float16)v0[0], (_Float16)v0[1], (_Float16)v0[2], (_Float16)v0[3],
               (_Float16)v1[0], (_Float16)v1[1], (_Float16)v1[2], (_Float16)v1[3]};
    const int byte = (r * 2048 + kg * 16) ^ ((r & 7) << 4);
    *(half8*)((char*)wlds + byte) = h;
  }
  // zero h buffer 0 (this WG's row-slice, all batches)
  for (int idx = tid; idx < B_ * 32; idx += 256) {
    const int b  = idx >> 5;
    const int rr = idx & 31;
    hbuf[((long)(0 * 2 + dir) * B_ + b) * H_ + rows0 + rr] = (_Float16)0.f;
  }

  cooperative_groups::grid_group grid = cooperative_groups::this_grid();
  grid.sync();

  const int lane = tid & 63;
  const int wv   = tid >> 6;
  const int mt   = wv >> 1;         // row half (0..1)
  const int nt   = wv & 1;          // batch half (0..1)
  const int lrow = lane & 15;
  const int lkg  = lane >> 4;       // 0..3
  const int arow = mt * 16 + lrow;  // row within 32-slice for A frags
  const int b_idx = nt * 16 + lrow; // batch for B frags / C cols
  const int r0 = rows0 + mt * 16 + lkg * 4;  // first of 4 output rows

  const int abase = arow * 2048;
  const int asw   = (arow & 7) << 4;

  for (int t = 0; t < S_; ++t) {
    const int p = t & 1;
    const _Float16* hrow = hbuf + ((long)(p * 2 + dir) * B_ + b_idx) * H_;

    floatx4 acc = {0.f, 0.f, 0.f, 0.f};
#pragma unroll 8
    for (int kt = 0; kt < 32; ++kt) {
      const int byte = (abase + kt * 64 + lkg * 16) ^ asw;
      half8 a = *(const half8*)((const char*)wlds + byte);
      half8 b = *(const half8*)(hrow + kt * 32 + lkg * 8);
      acc = __builtin_amdgcn_mfma_f32_16x16x32_f16(a, b, acc, 0, 0, 0);
    }

    const int sidx = dir ? (S_ - 1 - t) : t;
    const long o = ((long)b_idx * S_ + sidx) * (2 * H_) + dir * H_ + r0;
    floatx4 xpv = *(const floatx4*)(out + o);
    floatx4 hv;
#pragma unroll
    for (int v = 0; v < 4; ++v) hv[v] = tanhf(acc[v] + xpv[v]);
    *(floatx4*)(out + o) = hv;

    half4v hh = {(_Float16)hv[0], (_Float16)hv[1], (_Float16)hv[2], (_Float16)hv[3]};
    *(half4v*)(hbuf + ((long)((1 - p) * 2 + dir) * B_ + b_idx) * H_ + r0) = hh;

    grid.sync();
  }
}

// ---------------------------------------------------------------------------
extern "C" void kernel_launch(void* const* d_in, const int* in_sizes, int n_in,
                              void* d_out, int out_size, void* d_ws, size_t ws_size,
                              hipStream_t stream) {
  const float* x    = (const float*)d_in[0];
  const float* Wihf = (const float*)d_in[1];
  const float* Whhf = (const float*)d_in[2];
  const float* bihf = (const float*)d_in[3];
  const float* bhhf = (const float*)d_in[4];
  const float* Wihb = (const float*)d_in[5];
  const float* Whhb = (const float*)d_in[6];
  const float* bihb = (const float*)d_in[7];
  const float* bhhb = (const float*)d_in[8];
  float* out = (float*)d_out;

  // workspace layout
  char* ws = (char*)d_ws;
  _Float16* x16  = (_Float16*)ws;                                   // 32 MiB
  _Float16* w16  = (_Float16*)(ws + (size_t)33554432);              // 4 MiB [2][H][I]
  float*    bias = (float*)   (ws + (size_t)33554432 + 4194304);    // 8 KiB
  _Float16* hbuf = (_Float16*)(ws + (size_t)33554432 + 4194304 + 8192); // 256 KiB

  cvt_f32_f16<<<4096, 256, 0, stream>>>(x, x16, (long)M_TOT * I_);
  cvt_f32_f16<<<1024, 256, 0, stream>>>(Wihf, w16, (long)H_ * I_);
  cvt_f32_f16<<<1024, 256, 0, stream>>>(Wihb, w16 + (long)H_ * I_, (long)H_ * I_);
  bias_sum_kernel<<<4, 256, 0, stream>>>(bihf, bhhf, bihb, bhhb, bias);

  dim3 g(H_ / 128, M_TOT / 128, 2);  // (8, 128, 2)
  gemm_xp_kernel<<<g, 256, 0, stream>>>(x16, w16, bias, out);

  void* args[] = {(void*)&Whhf, (void*)&Whhb, (void*)&out, (void*)&hbuf};
  (void)hipLaunchCooperativeKernel((void*)scan_kernel, dim3(64), dim3(256),
                                   args, 0, stream);
}

// Round 3
// 5279.033 us; speedup vs baseline: 1.2864x; 1.2864x over previous
//
#include <hip/hip_runtime.h>

typedef _Float16 half8  __attribute__((ext_vector_type(8)));
typedef _Float16 half4v __attribute__((ext_vector_type(4)));
typedef float    floatx4 __attribute__((ext_vector_type(4)));
typedef unsigned long long u64;

#define B_ 32
#define S_ 512
#define I_ 1024
#define H_ 1024
#define M_TOT (B_ * S_)   // 16384

// ---------------------------------------------------------------------------
// fp32 -> fp16 conversion (vectorized, grid-stride), n multiple of 4
// ---------------------------------------------------------------------------
__global__ void cvt_f32_f16(const float* __restrict__ src, _Float16* __restrict__ dst, long n) {
  long i = ((long)blockIdx.x * blockDim.x + threadIdx.x) * 4;
  const long stride = (long)gridDim.x * blockDim.x * 4;
  for (; i < n; i += stride) {
    floatx4 v = *(const floatx4*)(src + i);
    half4v h = {(_Float16)v[0], (_Float16)v[1], (_Float16)v[2], (_Float16)v[3]};
    *(half4v*)(dst + i) = h;
  }
}

__global__ void bias_sum_kernel(const float* __restrict__ bihf, const float* __restrict__ bhhf,
                                const float* __restrict__ bihb, const float* __restrict__ bhhb,
                                float* __restrict__ bias, unsigned int* __restrict__ counter) {
  int i = blockIdx.x * blockDim.x + threadIdx.x;
  if (i == 0) {
    __hip_atomic_store(counter, 0u, __ATOMIC_RELAXED, __HIP_MEMORY_SCOPE_AGENT);
  }
  if (i < H_) {
    bias[i]      = bihf[i] + bhhf[i];
    bias[H_ + i] = bihb[i] + bhhb[i];
  }
}

// ---------------------------------------------------------------------------
// GEMM: xp[dir][m][n] = sum_k x16[m][k] * W16[dir][n][k] + bias[dir][n]
// stored into out[m*2048 + dir*1024 + n]  (xp lives in d_out, updated in place
// later by the scan).
// ---------------------------------------------------------------------------
__global__ void __launch_bounds__(256) gemm_xp_kernel(
    const _Float16* __restrict__ A,    // [16384][1024] x in f16
    const _Float16* __restrict__ W,    // [2][1024][1024] W_ih in f16
    const float*    __restrict__ bias, // [2][1024]
    float*          __restrict__ out)  // [16384][2048]
{
  __shared__ _Float16 alds[128 * 32];
  __shared__ _Float16 blds[128 * 32];

  const int dir = blockIdx.z;
  const int m0  = blockIdx.y * 128;
  const int n0  = blockIdx.x * 128;
  const int tid  = threadIdx.x;
  const int lane = tid & 63;
  const int wv   = tid >> 6;
  const int wm   = wv >> 1, wn = wv & 1;
  const int lrow = lane & 15;
  const int lkg  = lane >> 4;

  const _Float16* Wd = W + (long)dir * H_ * I_;

  floatx4 acc[4][4] = {};

  const int srow = tid >> 1;
  const int sseg = tid & 1;

  for (int kt = 0; kt < 32; ++kt) {
    __syncthreads();
    {
      const _Float16* srcA = A  + (long)(m0 + srow) * I_ + kt * 32 + sseg * 16;
      const _Float16* srcB = Wd + (long)(n0 + srow) * I_ + kt * 32 + sseg * 16;
      half8 a0 = *(const half8*)(srcA);
      half8 a1 = *(const half8*)(srcA + 8);
      half8 b0 = *(const half8*)(srcB);
      half8 b1 = *(const half8*)(srcB + 8);
      const int sw = (srow & 7) << 4;
      const int base = srow * 64 + sseg * 32;
      *(half8*)((char*)alds + ((base     ) ^ sw)) = a0;
      *(half8*)((char*)alds + ((base + 16) ^ sw)) = a1;
      *(half8*)((char*)blds + ((base     ) ^ sw)) = b0;
      *(half8*)((char*)blds + ((base + 16) ^ sw)) = b1;
    }
    __syncthreads();

    half8 af[4], bf[4];
#pragma unroll
    for (int mt = 0; mt < 4; ++mt) {
      int r = wm * 64 + mt * 16 + lrow;
      int byte = (r * 64 + lkg * 16) ^ ((r & 7) << 4);
      af[mt] = *(const half8*)((const char*)alds + byte);
    }
#pragma unroll
    for (int ntt = 0; ntt < 4; ++ntt) {
      int r = wn * 64 + ntt * 16 + lrow;
      int byte = (r * 64 + lkg * 16) ^ ((r & 7) << 4);
      bf[ntt] = *(const half8*)((const char*)blds + byte);
    }
#pragma unroll
    for (int mt = 0; mt < 4; ++mt)
#pragma unroll
      for (int ntt = 0; ntt < 4; ++ntt)
        acc[mt][ntt] = __builtin_amdgcn_mfma_f32_16x16x32_f16(af[mt], bf[ntt], acc[mt][ntt], 0, 0, 0);
  }

#pragma unroll
  for (int mt = 0; mt < 4; ++mt) {
    int mrow = m0 + wm * 64 + mt * 16 + lkg * 4;
#pragma unroll
    for (int ntt = 0; ntt < 4; ++ntt) {
      int n = n0 + wn * 64 + ntt * 16 + lrow;
      float bv = bias[dir * H_ + n];
#pragma unroll
      for (int v = 0; v < 4; ++v) {
        out[(long)(mrow + v) * (2 * H_) + dir * H_ + n] = acc[mt][ntt][v] + bv;
      }
    }
  }
}

// ---------------------------------------------------------------------------
// Recurrent scan with hand-rolled monotonic barrier.
// 64 WGs (dir = wg>>5, 32 output rows each), cooperative launch (co-residency
// guarantee only -- no grid.sync). h exchanged via relaxed agent-scope atomics
// (sc1 -> Infinity Cache, bypasses non-coherent per-XCD L2).
// ---------------------------------------------------------------------------
__global__ void __launch_bounds__(256) scan_kernel(
    const float* __restrict__ Whh_f,
    const float* __restrict__ Whh_b,
    float*       __restrict__ out,     // [B][S][2H]; holds xp on entry
    _Float16*    __restrict__ hbuf,    // [2 buf][2 dir][B][H] f16
    unsigned int* __restrict__ counter)
{
  __shared__ _Float16 wlds[32 * 1024];  // 64 KiB

  const int w     = blockIdx.x;
  const int dir   = w >> 5;
  const int rows0 = (w & 31) * 32;
  const float* Whh = dir ? Whh_b : Whh_f;
  const int tid = threadIdx.x;

  // stage W_hh rows [rows0, rows0+32) as f16, swizzled: byte ^= (row&7)<<4
  for (int idx = tid; idx < 32 * 128; idx += 256) {
    const int r  = idx >> 7;
    const int kg = idx & 127;
    const float* src = Whh + (long)(rows0 + r) * H_ + kg * 8;
    floatx4 v0 = *(const floatx4*)(src);
    floatx4 v1 = *(const floatx4*)(src + 4);
    half8 h = {(_Float16)v0[0], (_Float16)v0[1], (_Float16)v0[2], (_Float16)v0[3],
               (_Float16)v1[0], (_Float16)v1[1], (_Float16)v1[2], (_Float16)v1[3]};
    const int byte = (r * 2048 + kg * 16) ^ ((r & 7) << 4);
    *(half8*)((char*)wlds + byte) = h;
  }

  // zero own slice of h buffer 0 (all batches) via agent-scope stores
  for (int idx = tid; idx < 256; idx += 256) {
    const int b  = idx >> 3;   // 0..31
    const int rg = idx & 7;    // 8 groups of 4 halves = 32 rows
    u64* p = (u64*)(hbuf + ((long)(0 * 2 + dir) * B_ + b) * H_ + rows0 + rg * 4);
    __hip_atomic_store(p, (u64)0, __ATOMIC_RELAXED, __HIP_MEMORY_SCOPE_AGENT);
  }

  const int lane = tid & 63;
  const int wv   = tid >> 6;
  const int mt   = wv >> 1;
  const int nt   = wv & 1;
  const int lrow = lane & 15;
  const int lkg  = lane >> 4;
  const int arow = mt * 16 + lrow;
  const int b_idx = nt * 16 + lrow;
  const int r0 = rows0 + mt * 16 + lkg * 4;

  const int abase = arow * 2048;
  const int asw   = (arow & 7) << 4;

  unsigned int bar = 64;  // prologue target

  // prologue barrier: h0 + LDS-resident W visible
  asm volatile("s_waitcnt vmcnt(0)" ::: "memory");
  __syncthreads();
  if (tid == 0) {
    __hip_atomic_fetch_add(counter, 1u, __ATOMIC_RELEASE, __HIP_MEMORY_SCOPE_AGENT);
    while (__hip_atomic_load(counter, __ATOMIC_RELAXED, __HIP_MEMORY_SCOPE_AGENT) < bar) {}
  }
  __syncthreads();

  // 1-step-ahead xp prefetch
  long o_next;
  {
    const int sidx = dir ? (S_ - 1) : 0;
    o_next = ((long)b_idx * S_ + sidx) * (2 * H_) + dir * H_ + r0;
  }
  floatx4 xp_next = *(const floatx4*)(out + o_next);

  for (int t = 0; t < S_; ++t) {
    const int p = t & 1;
    const long o = o_next;
    floatx4 xpv = xp_next;

    if (t + 1 < S_) {
      const int sidx1 = dir ? (S_ - 2 - t) : (t + 1);
      o_next = ((long)b_idx * S_ + sidx1) * (2 * H_) + dir * H_ + r0;
      xp_next = *(const floatx4*)(out + o_next);
    }

    u64* hrow = (u64*)(hbuf + ((long)(p * 2 + dir) * B_ + b_idx) * H_);

    floatx4 acc[4] = {};
#pragma unroll
    for (int kt = 0; kt < 32; ++kt) {
      const int byte = (abase + kt * 64 + lkg * 16) ^ asw;
      half8 a = *(const half8*)((const char*)wlds + byte);
      u64 u0 = __hip_atomic_load(hrow + kt * 8 + lkg * 2,     __ATOMIC_RELAXED, __HIP_MEMORY_SCOPE_AGENT);
      u64 u1 = __hip_atomic_load(hrow + kt * 8 + lkg * 2 + 1, __ATOMIC_RELAXED, __HIP_MEMORY_SCOPE_AGENT);
      union { u64 u[2]; half8 h; } bb;
      bb.u[0] = u0; bb.u[1] = u1;
      acc[kt & 3] = __builtin_amdgcn_mfma_f32_16x16x32_f16(a, bb.h, acc[kt & 3], 0, 0, 0);
    }

    floatx4 s4 = (acc[0] + acc[1]) + (acc[2] + acc[3]);
    floatx4 hv;
#pragma unroll
    for (int v = 0; v < 4; ++v) {
      float z = s4[v] + xpv[v];
      hv[v] = 1.f - 2.f / (__expf(2.f * z) + 1.f);   // tanh(z)
    }
    *(floatx4*)(out + o) = hv;

    if (t < S_ - 1) {
      union { half4v h; u64 u; } hh;
      hh.h = half4v{(_Float16)hv[0], (_Float16)hv[1], (_Float16)hv[2], (_Float16)hv[3]};
      u64* dst = (u64*)(hbuf + ((long)((1 - p) * 2 + dir) * B_ + b_idx) * H_ + r0);
      __hip_atomic_store(dst, hh.u, __ATOMIC_RELAXED, __HIP_MEMORY_SCOPE_AGENT);

      bar += 64;
      asm volatile("s_waitcnt vmcnt(0)" ::: "memory");
      __syncthreads();
      if (tid == 0) {
        __hip_atomic_fetch_add(counter, 1u, __ATOMIC_RELEASE, __HIP_MEMORY_SCOPE_AGENT);
        while (__hip_atomic_load(counter, __ATOMIC_RELAXED, __HIP_MEMORY_SCOPE_AGENT) < bar) {}
      }
      __syncthreads();
    }
  }
}

// ---------------------------------------------------------------------------
extern "C" void kernel_launch(void* const* d_in, const int* in_sizes, int n_in,
                              void* d_out, int out_size, void* d_ws, size_t ws_size,
                              hipStream_t stream) {
  const float* x    = (const float*)d_in[0];
  const float* Wihf = (const float*)d_in[1];
  const float* Whhf = (const float*)d_in[2];
  const float* bihf = (const float*)d_in[3];
  const float* bhhf = (const float*)d_in[4];
  const float* Wihb = (const float*)d_in[5];
  const float* Whhb = (const float*)d_in[6];
  const float* bihb = (const float*)d_in[7];
  const float* bhhb = (const float*)d_in[8];
  float* out = (float*)d_out;

  // workspace layout
  char* ws = (char*)d_ws;
  _Float16* x16  = (_Float16*)ws;                                        // 32 MiB
  _Float16* w16  = (_Float16*)(ws + (size_t)33554432);                   // 4 MiB
  float*    bias = (float*)   (ws + (size_t)33554432 + 4194304);         // 8 KiB
  _Float16* hbuf = (_Float16*)(ws + (size_t)33554432 + 4194304 + 8192);  // 256 KiB
  unsigned int* counter = (unsigned int*)(ws + (size_t)33554432 + 4194304 + 8192 + 262144);

  cvt_f32_f16<<<4096, 256, 0, stream>>>(x, x16, (long)M_TOT * I_);
  cvt_f32_f16<<<1024, 256, 0, stream>>>(Wihf, w16, (long)H_ * I_);
  cvt_f32_f16<<<1024, 256, 0, stream>>>(Wihb, w16 + (long)H_ * I_, (long)H_ * I_);
  bias_sum_kernel<<<4, 256, 0, stream>>>(bihf, bhhf, bihb, bhhb, bias, counter);

  dim3 g(H_ / 128, M_TOT / 128, 2);
  gemm_xp_kernel<<<g, 256, 0, stream>>>(x16, w16, bias, out);

  void* args[] = {(void*)&Whhf, (void*)&Whhb, (void*)&out, (void*)&hbuf, (void*)&counter};
  (void)hipLaunchCooperativeKernel((void*)scan_kernel, dim3(64), dim3(256),
                                   args, 0, stream);
}

// Round 4
// 4863.828 us; speedup vs baseline: 1.3962x; 1.0854x over previous
//
#include <hip/hip_runtime.h>

typedef _Float16 half8  __attribute__((ext_vector_type(8)));
typedef _Float16 half4v __attribute__((ext_vector_type(4)));
typedef float    floatx4 __attribute__((ext_vector_type(4)));
typedef unsigned long long u64;

#define B_ 32
#define S_ 512
#define I_ 1024
#define H_ 1024
#define M_TOT (B_ * S_)   // 16384

// ---------------------------------------------------------------------------
// fp32 -> fp16 conversion (vectorized, grid-stride), n multiple of 4
// ---------------------------------------------------------------------------
__global__ void cvt_f32_f16(const float* __restrict__ src, _Float16* __restrict__ dst, long n) {
  long i = ((long)blockIdx.x * blockDim.x + threadIdx.x) * 4;
  const long stride = (long)gridDim.x * blockDim.x * 4;
  for (; i < n; i += stride) {
    floatx4 v = *(const floatx4*)(src + i);
    half4v h = {(_Float16)v[0], (_Float16)v[1], (_Float16)v[2], (_Float16)v[3]};
    *(half4v*)(dst + i) = h;
  }
}

__global__ void bias_sum_kernel(const float* __restrict__ bihf, const float* __restrict__ bhhf,
                                const float* __restrict__ bihb, const float* __restrict__ bhhb,
                                float* __restrict__ bias, unsigned int* __restrict__ counter) {
  int i = blockIdx.x * blockDim.x + threadIdx.x;
  if (i == 0) {
    __hip_atomic_store(counter,      0u, __ATOMIC_RELAXED, __HIP_MEMORY_SCOPE_AGENT);
    __hip_atomic_store(counter + 32, 0u, __ATOMIC_RELAXED, __HIP_MEMORY_SCOPE_AGENT);
  }
  if (i < H_) {
    bias[i]      = bihf[i] + bhhf[i];
    bias[H_ + i] = bihb[i] + bhhb[i];
  }
}

// ---------------------------------------------------------------------------
// GEMM: xp[dir][m][n] = sum_k x16[m][k] * W16[dir][n][k] + bias[dir][n]
// stored into out[m*2048 + dir*1024 + n]  (xp lives in d_out, updated in place
// later by the scan).
// ---------------------------------------------------------------------------
__global__ void __launch_bounds__(256) gemm_xp_kernel(
    const _Float16* __restrict__ A,    // [16384][1024] x in f16
    const _Float16* __restrict__ W,    // [2][1024][1024] W_ih in f16
    const float*    __restrict__ bias, // [2][1024]
    float*          __restrict__ out)  // [16384][2048]
{
  __shared__ _Float16 alds[128 * 32];
  __shared__ _Float16 blds[128 * 32];

  const int dir = blockIdx.z;
  const int m0  = blockIdx.y * 128;
  const int n0  = blockIdx.x * 128;
  const int tid  = threadIdx.x;
  const int lane = tid & 63;
  const int wv   = tid >> 6;
  const int wm   = wv >> 1, wn = wv & 1;
  const int lrow = lane & 15;
  const int lkg  = lane >> 4;

  const _Float16* Wd = W + (long)dir * H_ * I_;

  floatx4 acc[4][4] = {};

  const int srow = tid >> 1;
  const int sseg = tid & 1;

  for (int kt = 0; kt < 32; ++kt) {
    __syncthreads();
    {
      const _Float16* srcA = A  + (long)(m0 + srow) * I_ + kt * 32 + sseg * 16;
      const _Float16* srcB = Wd + (long)(n0 + srow) * I_ + kt * 32 + sseg * 16;
      half8 a0 = *(const half8*)(srcA);
      half8 a1 = *(const half8*)(srcA + 8);
      half8 b0 = *(const half8*)(srcB);
      half8 b1 = *(const half8*)(srcB + 8);
      const int sw = (srow & 7) << 4;
      const int base = srow * 64 + sseg * 32;
      *(half8*)((char*)alds + ((base     ) ^ sw)) = a0;
      *(half8*)((char*)alds + ((base + 16) ^ sw)) = a1;
      *(half8*)((char*)blds + ((base     ) ^ sw)) = b0;
      *(half8*)((char*)blds + ((base + 16) ^ sw)) = b1;
    }
    __syncthreads();

    half8 af[4], bf[4];
#pragma unroll
    for (int mt = 0; mt < 4; ++mt) {
      int r = wm * 64 + mt * 16 + lrow;
      int byte = (r * 64 + lkg * 16) ^ ((r & 7) << 4);
      af[mt] = *(const half8*)((const char*)alds + byte);
    }
#pragma unroll
    for (int ntt = 0; ntt < 4; ++ntt) {
      int r = wn * 64 + ntt * 16 + lrow;
      int byte = (r * 64 + lkg * 16) ^ ((r & 7) << 4);
      bf[ntt] = *(const half8*)((const char*)blds + byte);
    }
#pragma unroll
    for (int mt = 0; mt < 4; ++mt)
#pragma unroll
      for (int ntt = 0; ntt < 4; ++ntt)
        acc[mt][ntt] = __builtin_amdgcn_mfma_f32_16x16x32_f16(af[mt], bf[ntt], acc[mt][ntt], 0, 0, 0);
  }

#pragma unroll
  for (int mt = 0; mt < 4; ++mt) {
    int mrow = m0 + wm * 64 + mt * 16 + lkg * 4;
#pragma unroll
    for (int ntt = 0; ntt < 4; ++ntt) {
      int n = n0 + wn * 64 + ntt * 16 + lrow;
      float bv = bias[dir * H_ + n];
#pragma unroll
      for (int v = 0; v < 4; ++v) {
        out[(long)(mrow + v) * (2 * H_) + dir * H_ + n] = acc[mt][ntt][v] + bv;
      }
    }
  }
}

// ---------------------------------------------------------------------------
// Recurrent scan with hand-rolled monotonic barrier (RELAXED add -- no
// buffer_wbl2; ordering of the sc1 h-store is by explicit s_waitcnt vmcnt(0)).
// Per-direction counters: fwd and bwd pipelines are fully independent.
// 64 WGs (dir = wg>>5, 32 output rows each), cooperative launch for
// co-residency only. h exchanged via relaxed agent-scope (sc1) atomics.
// ---------------------------------------------------------------------------
__global__ void __launch_bounds__(256) scan_kernel(
    const float* __restrict__ Whh_f,
    const float* __restrict__ Whh_b,
    float*       __restrict__ out,     // [B][S][2H]; holds xp on entry
    _Float16*    __restrict__ hbuf,    // [2 buf][2 dir][B][H] f16
    unsigned int* __restrict__ counter) // [2] on separate 128B lines
{
  __shared__ _Float16 wlds[32 * 1024];  // 64 KiB

  const int w     = blockIdx.x;
  const int dir   = w >> 5;
  const int rows0 = (w & 31) * 32;
  const float* Whh = dir ? Whh_b : Whh_f;
  unsigned int* ctr = counter + dir * 32;
  const int tid = threadIdx.x;

  // stage W_hh rows [rows0, rows0+32) as f16, swizzled: byte ^= (row&7)<<4
  for (int idx = tid; idx < 32 * 128; idx += 256) {
    const int r  = idx >> 7;
    const int kg = idx & 127;
    const float* src = Whh + (long)(rows0 + r) * H_ + kg * 8;
    floatx4 v0 = *(const floatx4*)(src);
    floatx4 v1 = *(const floatx4*)(src + 4);
    half8 h = {(_Float16)v0[0], (_Float16)v0[1], (_Float16)v0[2], (_Float16)v0[3],
               (_Float16)v1[0], (_Float16)v1[1], (_Float16)v1[2], (_Float16)v1[3]};
    const int byte = (r * 2048 + kg * 16) ^ ((r & 7) << 4);
    *(half8*)((char*)wlds + byte) = h;
  }

  // zero own slice of h buffer 0 (all batches) via agent-scope stores
  for (int idx = tid; idx < 256; idx += 256) {
    const int b  = idx >> 3;   // 0..31
    const int rg = idx & 7;    // 8 groups of 4 halves = 32 rows
    u64* p = (u64*)(hbuf + ((long)(0 * 2 + dir) * B_ + b) * H_ + rows0 + rg * 4);
    __hip_atomic_store(p, (u64)0, __ATOMIC_RELAXED, __HIP_MEMORY_SCOPE_AGENT);
  }

  const int lane = tid & 63;
  const int wv   = tid >> 6;
  const int mt   = wv >> 1;
  const int nt   = wv & 1;
  const int lrow = lane & 15;
  const int lkg  = lane >> 4;
  const int arow = mt * 16 + lrow;
  const int b_idx = nt * 16 + lrow;
  const int r0 = rows0 + mt * 16 + lkg * 4;

  const int abase = arow * 2048;
  const int asw   = (arow & 7) << 4;

  unsigned int bar = 32;  // prologue target (per-direction barrier)

  // prologue barrier: h0 + LDS-resident W visible
  asm volatile("s_waitcnt vmcnt(0)" ::: "memory");
  __syncthreads();
  if (tid == 0) {
    __hip_atomic_fetch_add(ctr, 1u, __ATOMIC_RELAXED, __HIP_MEMORY_SCOPE_AGENT);
    while (__hip_atomic_load(ctr, __ATOMIC_RELAXED, __HIP_MEMORY_SCOPE_AGENT) < bar) {
      __builtin_amdgcn_s_sleep(1);
    }
  }
  __syncthreads();

  // 1-step-ahead xp prefetch
  long o_next;
  {
    const int sidx = dir ? (S_ - 1) : 0;
    o_next = ((long)b_idx * S_ + sidx) * (2 * H_) + dir * H_ + r0;
  }
  floatx4 xp_next = *(const floatx4*)(out + o_next);

  for (int t = 0; t < S_; ++t) {
    const int p = t & 1;
    const long o = o_next;
    floatx4 xpv = xp_next;

    if (t + 1 < S_) {
      const int sidx1 = dir ? (S_ - 2 - t) : (t + 1);
      o_next = ((long)b_idx * S_ + sidx1) * (2 * H_) + dir * H_ + r0;
      xp_next = *(const floatx4*)(out + o_next);
    }

    u64* hrow = (u64*)(hbuf + ((long)(p * 2 + dir) * B_ + b_idx) * H_);

    floatx4 acc[4] = {};
#pragma unroll
    for (int kt = 0; kt < 32; ++kt) {
      const int byte = (abase + kt * 64 + lkg * 16) ^ asw;
      half8 a = *(const half8*)((const char*)wlds + byte);
      u64 u0 = __hip_atomic_load(hrow + kt * 8 + lkg * 2,     __ATOMIC_RELAXED, __HIP_MEMORY_SCOPE_AGENT);
      u64 u1 = __hip_atomic_load(hrow + kt * 8 + lkg * 2 + 1, __ATOMIC_RELAXED, __HIP_MEMORY_SCOPE_AGENT);
      union { u64 u[2]; half8 h; } bb;
      bb.u[0] = u0; bb.u[1] = u1;
      acc[kt & 3] = __builtin_amdgcn_mfma_f32_16x16x32_f16(a, bb.h, acc[kt & 3], 0, 0, 0);
    }

    floatx4 s4 = (acc[0] + acc[1]) + (acc[2] + acc[3]);
    floatx4 hv;
#pragma unroll
    for (int v = 0; v < 4; ++v) {
      float z = s4[v] + xpv[v];
      hv[v] = 1.f - 2.f / (__expf(2.f * z) + 1.f);   // tanh(z)
    }
    *(floatx4*)(out + o) = hv;

    if (t < S_ - 1) {
      union { half4v h; u64 u; } hh;
      hh.h = half4v{(_Float16)hv[0], (_Float16)hv[1], (_Float16)hv[2], (_Float16)hv[3]};
      u64* dst = (u64*)(hbuf + ((long)((1 - p) * 2 + dir) * B_ + b_idx) * H_ + r0);
      __hip_atomic_store(dst, hh.u, __ATOMIC_RELAXED, __HIP_MEMORY_SCOPE_AGENT);

      bar += 32;
      asm volatile("s_waitcnt vmcnt(0)" ::: "memory");
      __syncthreads();
      if (tid == 0) {
        __hip_atomic_fetch_add(ctr, 1u, __ATOMIC_RELAXED, __HIP_MEMORY_SCOPE_AGENT);
        while (__hip_atomic_load(ctr, __ATOMIC_RELAXED, __HIP_MEMORY_SCOPE_AGENT) < bar) {
          __builtin_amdgcn_s_sleep(1);
        }
      }
      __syncthreads();
    }
  }
}

// ---------------------------------------------------------------------------
extern "C" void kernel_launch(void* const* d_in, const int* in_sizes, int n_in,
                              void* d_out, int out_size, void* d_ws, size_t ws_size,
                              hipStream_t stream) {
  const float* x    = (const float*)d_in[0];
  const float* Wihf = (const float*)d_in[1];
  const float* Whhf = (const float*)d_in[2];
  const float* bihf = (const float*)d_in[3];
  const float* bhhf = (const float*)d_in[4];
  const float* Wihb = (const float*)d_in[5];
  const float* Whhb = (const float*)d_in[6];
  const float* bihb = (const float*)d_in[7];
  const float* bhhb = (const float*)d_in[8];
  float* out = (float*)d_out;

  // workspace layout
  char* ws = (char*)d_ws;
  _Float16* x16  = (_Float16*)ws;                                        // 32 MiB
  _Float16* w16  = (_Float16*)(ws + (size_t)33554432);                   // 4 MiB
  float*    bias = (float*)   (ws + (size_t)33554432 + 4194304);         // 8 KiB
  _Float16* hbuf = (_Float16*)(ws + (size_t)33554432 + 4194304 + 8192);  // 256 KiB
  unsigned int* counter = (unsigned int*)(ws + (size_t)33554432 + 4194304 + 8192 + 262144);

  cvt_f32_f16<<<4096, 256, 0, stream>>>(x, x16, (long)M_TOT * I_);
  cvt_f32_f16<<<1024, 256, 0, stream>>>(Wihf, w16, (long)H_ * I_);
  cvt_f32_f16<<<1024, 256, 0, stream>>>(Wihb, w16 + (long)H_ * I_, (long)H_ * I_);
  bias_sum_kernel<<<4, 256, 0, stream>>>(bihf, bhhf, bihb, bhhb, bias, counter);

  dim3 g(H_ / 128, M_TOT / 128, 2);
  gemm_xp_kernel<<<g, 256, 0, stream>>>(x16, w16, bias, out);

  void* args[] = {(void*)&Whhf, (void*)&Whhb, (void*)&out, (void*)&hbuf, (void*)&counter};
  (void)hipLaunchCooperativeKernel((void*)scan_kernel, dim3(64), dim3(256),
                                   args, 0, stream);
}

// Round 6
// 2445.813 us; speedup vs baseline: 2.7765x; 1.9886x over previous
//
#include <hip/hip_runtime.h>

typedef _Float16 half8  __attribute__((ext_vector_type(8)));
typedef _Float16 half4v __attribute__((ext_vector_type(4)));
typedef float    floatx4 __attribute__((ext_vector_type(4)));
typedef unsigned long long u64;

#define B_ 32
#define S_ 512
#define I_ 1024
#define H_ 1024
#define M_TOT (B_ * S_)   // 16384

// ---------------------------------------------------------------------------
// fp32 -> fp16 conversion (vectorized, grid-stride), n multiple of 4
// ---------------------------------------------------------------------------
__global__ void cvt_f32_f16(const float* __restrict__ src, _Float16* __restrict__ dst, long n) {
  long i = ((long)blockIdx.x * blockDim.x + threadIdx.x) * 4;
  const long stride = (long)gridDim.x * blockDim.x * 4;
  for (; i < n; i += stride) {
    floatx4 v = *(const floatx4*)(src + i);
    half4v h = {(_Float16)v[0], (_Float16)v[1], (_Float16)v[2], (_Float16)v[3]};
    *(half4v*)(dst + i) = h;
  }
}

__global__ void bias_sum_kernel(const float* __restrict__ bihf, const float* __restrict__ bhhf,
                                const float* __restrict__ bihb, const float* __restrict__ bhhb,
                                float* __restrict__ bias, unsigned int* __restrict__ counter) {
  int i = blockIdx.x * blockDim.x + threadIdx.x;
  if (i == 0) {
    __hip_atomic_store(counter,      0u, __ATOMIC_RELAXED, __HIP_MEMORY_SCOPE_AGENT);
    __hip_atomic_store(counter + 32, 0u, __ATOMIC_RELAXED, __HIP_MEMORY_SCOPE_AGENT);
  }
  if (i < H_) {
    bias[i]      = bihf[i] + bhhf[i];
    bias[H_ + i] = bihb[i] + bhhb[i];
  }
}

// ---------------------------------------------------------------------------
// GEMM: xp[dir][m][n] = sum_k x16[m][k] * W16[dir][n][k] + bias[dir][n]
// stored into out[m*2048 + dir*1024 + n] (xp lives in d_out; scan updates it
// in place).
// ---------------------------------------------------------------------------
__global__ void __launch_bounds__(256) gemm_xp_kernel(
    const _Float16* __restrict__ A,
    const _Float16* __restrict__ W,
    const float*    __restrict__ bias,
    float*          __restrict__ out)
{
  __shared__ _Float16 alds[128 * 32];
  __shared__ _Float16 blds[128 * 32];

  const int dir = blockIdx.z;
  const int m0  = blockIdx.y * 128;
  const int n0  = blockIdx.x * 128;
  const int tid  = threadIdx.x;
  const int lane = tid & 63;
  const int wv   = tid >> 6;
  const int wm   = wv >> 1, wn = wv & 1;
  const int lrow = lane & 15;
  const int lkg  = lane >> 4;

  const _Float16* Wd = W + (long)dir * H_ * I_;

  floatx4 acc[4][4] = {};

  const int srow = tid >> 1;
  const int sseg = tid & 1;

  for (int kt = 0; kt < 32; ++kt) {
    __syncthreads();
    {
      const _Float16* srcA = A  + (long)(m0 + srow) * I_ + kt * 32 + sseg * 16;
      const _Float16* srcB = Wd + (long)(n0 + srow) * I_ + kt * 32 + sseg * 16;
      half8 a0 = *(const half8*)(srcA);
      half8 a1 = *(const half8*)(srcA + 8);
      half8 b0 = *(const half8*)(srcB);
      half8 b1 = *(const half8*)(srcB + 8);
      const int sw = (srow & 7) << 4;
      const int base = srow * 64 + sseg * 32;
      *(half8*)((char*)alds + ((base     ) ^ sw)) = a0;
      *(half8*)((char*)alds + ((base + 16) ^ sw)) = a1;
      *(half8*)((char*)blds + ((base     ) ^ sw)) = b0;
      *(half8*)((char*)blds + ((base + 16) ^ sw)) = b1;
    }
    __syncthreads();

    half8 af[4], bf[4];
#pragma unroll
    for (int mt = 0; mt < 4; ++mt) {
      int r = wm * 64 + mt * 16 + lrow;
      int byte = (r * 64 + lkg * 16) ^ ((r & 7) << 4);
      af[mt] = *(const half8*)((const char*)alds + byte);
    }
#pragma unroll
    for (int ntt = 0; ntt < 4; ++ntt) {
      int r = wn * 64 + ntt * 16 + lrow;
      int byte = (r * 64 + lkg * 16) ^ ((r & 7) << 4);
      bf[ntt] = *(const half8*)((const char*)blds + byte);
    }
#pragma unroll
    for (int mt = 0; mt < 4; ++mt)
#pragma unroll
      for (int ntt = 0; ntt < 4; ++ntt)
        acc[mt][ntt] = __builtin_amdgcn_mfma_f32_16x16x32_f16(af[mt], bf[ntt], acc[mt][ntt], 0, 0, 0);
  }

#pragma unroll
  for (int mt = 0; mt < 4; ++mt) {
    int mrow = m0 + wm * 64 + mt * 16 + lkg * 4;
#pragma unroll
    for (int ntt = 0; ntt < 4; ++ntt) {
      int n = n0 + wn * 64 + ntt * 16 + lrow;
      float bv = bias[dir * H_ + n];
#pragma unroll
      for (int v = 0; v < 4; ++v) {
        out[(long)(mrow + v) * (2 * H_) + dir * H_ + n] = acc[mt][ntt][v] + bv;
      }
    }
  }
}

// ---------------------------------------------------------------------------
// Recurrent scan (R4 structure, proven): 64 WGs, dir = wg>>5, 32 rows each.
// All cross-WG traffic at agent scope (sc1 -> MALL). Monotonic per-direction
// counter barrier with RELAXED add (ordering by explicit s_waitcnt vmcnt(0)).
// NEW vs R4:
//  - waves = (nt batch-half, kh K-half): each wave loads only its K-half of h
//    (halves h traffic) and computes BOTH 16-row tiles (A reused from LDS).
//  - h loads batched: 16 inline-asm global_load_dwordx4 sc1 issued
//    back-to-back, single vmcnt(0) -> ONE exposed MALL latency per step
//    (the compiler serialized the per-kt atomic loads in R4: ~32 exposed
//    latencies = the 9.2 us/step).
//  - kh partial sums exchanged via 4 KB LDS.
// ---------------------------------------------------------------------------
__global__ void __launch_bounds__(256, 1) scan_kernel(
    const float* __restrict__ Whh_f,
    const float* __restrict__ Whh_b,
    float*       __restrict__ out,     // [B][S][2H]; holds xp on entry
    _Float16*    __restrict__ hbuf,    // [2 buf][2 dir][B][H] f16
    unsigned int* __restrict__ counter) // per-dir, 128 B apart
{
  __shared__ _Float16 wlds[32 * 1024];   // 64 KiB
  __shared__ floatx4  redlds[4 * 64];    // 4 KiB: [tile*2+nt][lane]

  const int w     = blockIdx.x;
  const int dir   = w >> 5;
  const int rows0 = (w & 31) * 32;
  const float* Whh = dir ? Whh_b : Whh_f;
  unsigned int* ctr = counter + dir * 32;
  const int tid = threadIdx.x;

  // stage W_hh rows [rows0, rows0+32) as f16, swizzled: byte ^= (row&7)<<4
  for (int idx = tid; idx < 32 * 128; idx += 256) {
    const int r  = idx >> 7;
    const int kg = idx & 127;
    const float* src = Whh + (long)(rows0 + r) * H_ + kg * 8;
    floatx4 v0 = *(const floatx4*)(src);
    floatx4 v1 = *(const floatx4*)(src + 4);
    half8 h = {(_Float16)v0[0], (_Float16)v0[1], (_Float16)v0[2], (_Float16)v0[3],
               (_Float16)v1[0], (_Float16)v1[1], (_Float16)v1[2], (_Float16)v1[3]};
    const int byte = (r * 2048 + kg * 16) ^ ((r & 7) << 4);
    *(half8*)((char*)wlds + byte) = h;
  }

  // zero own slice of h buffer 0 (all batches, 32 rows) via agent-scope stores
  {
    const int b  = tid >> 3;   // 0..31
    const int rg = tid & 7;    // 8 u64 groups of 4 halves = 32 rows
    u64* p = (u64*)(hbuf + ((long)(0 * 2 + dir) * B_ + b) * H_ + rows0 + rg * 4);
    __hip_atomic_store(p, (u64)0, __ATOMIC_RELAXED, __HIP_MEMORY_SCOPE_AGENT);
  }

  // wave/lane roles
  const int lane = tid & 63;
  const int wv   = tid >> 6;
  const int nt   = wv & 1;          // batch half
  const int kh   = wv >> 1;         // K half
  const int lrow = lane & 15;
  const int lkg  = lane >> 4;       // 0..3
  const int b_idx = nt * 16 + lrow; // batch
  const int kbase = kh * 512;       // K-half start (halves)
  const int r0    = rows0 + kh * 16 + lkg * 4;  // this lane's 4 output rows (tile kh)
  const int asw   = (lrow & 7) << 4;            // same for rows lrow and 16+lrow
  const int abase0 = lrow * 2048 + kbase * 2;        // tile0 row byte base
  const int abase1 = (16 + lrow) * 2048 + kbase * 2; // tile1 row byte base

  unsigned int bar = 32;  // per-direction barrier target

  // prologue barrier: h0 + LDS-resident W visible
  asm volatile("s_waitcnt vmcnt(0)" ::: "memory");
  __syncthreads();
  if (tid == 0) {
    __hip_atomic_fetch_add(ctr, 1u, __ATOMIC_RELAXED, __HIP_MEMORY_SCOPE_AGENT);
    while (__hip_atomic_load(ctr, __ATOMIC_RELAXED, __HIP_MEMORY_SCOPE_AGENT) < bar) {
      __builtin_amdgcn_s_sleep(1);
    }
  }
  __syncthreads();

  // 1-step-ahead xp prefetch (plain load; only this lane ever touches out[o])
  long o_next;
  {
    const int sidx = dir ? (S_ - 1) : 0;
    o_next = ((long)b_idx * S_ + sidx) * (2 * H_) + dir * H_ + r0;
  }
  floatx4 xp_next = *(const floatx4*)(out + o_next);

  for (int t = 0; t < S_; ++t) {
    const int p = t & 1;

    // ---- batched agent-scope h loads: 16 x dwordx4, one exposed latency ----
    const _Float16* hp = hbuf + ((long)(p * 2 + dir) * B_ + b_idx) * H_ + kbase + lkg * 8;
    half8 hr[16];
#pragma unroll
    for (int kt = 0; kt < 16; ++kt) {
      asm volatile("global_load_dwordx4 %0, %1, off offset:%2 sc1"
                   : "=v"(hr[kt]) : "v"(hp), "i"(kt * 64) : "memory");
    }
    asm volatile("s_waitcnt vmcnt(0)" ::: "memory");
    __builtin_amdgcn_sched_barrier(0);

    // ---- MFMA: both row tiles, this K-half ----
    floatx4 acc0 = {}, acc1 = {};
#pragma unroll
    for (int kt = 0; kt < 16; ++kt) {
      const int koff = kt * 64 + lkg * 16;
      half8 a0 = *(const half8*)((const char*)wlds + ((abase0 + koff) ^ asw));
      half8 a1 = *(const half8*)((const char*)wlds + ((abase1 + koff) ^ asw));
      acc0 = __builtin_amdgcn_mfma_f32_16x16x32_f16(a0, hr[kt], acc0, 0, 0, 0);
      acc1 = __builtin_amdgcn_mfma_f32_16x16x32_f16(a1, hr[kt], acc1, 0, 0, 0);
    }

    // ---- kh partial-sum exchange: wave kh owns tile kh, ships tile 1-kh ----
    redlds[((1 - kh) * 2 + nt) * 64 + lane] = kh ? acc0 : acc1;
    __syncthreads();
    floatx4 tot = (kh ? acc1 : acc0) + redlds[(kh * 2 + nt) * 64 + lane];

    const long o = o_next;
    const floatx4 xpv = xp_next;
    if (t + 1 < S_) {
      const int sidx1 = dir ? (S_ - 2 - t) : (t + 1);
      o_next = ((long)b_idx * S_ + sidx1) * (2 * H_) + dir * H_ + r0;
      xp_next = *(const floatx4*)(out + o_next);
    }

    floatx4 hv;
#pragma unroll
    for (int v = 0; v < 4; ++v) {
      float z = tot[v] + xpv[v];
      hv[v] = 1.f - 2.f / (__expf(2.f * z) + 1.f);   // tanh(z)
    }
    *(floatx4*)(out + o) = hv;

    if (t + 1 < S_) {
      union { half4v h; u64 u; } hh;
      hh.h = half4v{(_Float16)hv[0], (_Float16)hv[1], (_Float16)hv[2], (_Float16)hv[3]};
      u64* dst = (u64*)(hbuf + ((long)((1 - p) * 2 + dir) * B_ + b_idx) * H_ + r0);
      __hip_atomic_store(dst, hh.u, __ATOMIC_RELAXED, __HIP_MEMORY_SCOPE_AGENT);
    } else {
      break;  // last step: no barrier needed
    }

    bar += 32;
    asm volatile("s_waitcnt vmcnt(0)" ::: "memory");
    __syncthreads();
    if (tid == 0) {
      __hip_atomic_fetch_add(ctr, 1u, __ATOMIC_RELAXED, __HIP_MEMORY_SCOPE_AGENT);
      while (__hip_atomic_load(ctr, __ATOMIC_RELAXED, __HIP_MEMORY_SCOPE_AGENT) < bar) {
        __builtin_amdgcn_s_sleep(1);
      }
    }
    __syncthreads();
  }
}

// ---------------------------------------------------------------------------
extern "C" void kernel_launch(void* const* d_in, const int* in_sizes, int n_in,
                              void* d_out, int out_size, void* d_ws, size_t ws_size,
                              hipStream_t stream) {
  const float* x    = (const float*)d_in[0];
  const float* Wihf = (const float*)d_in[1];
  const float* Whhf = (const float*)d_in[2];
  const float* bihf = (const float*)d_in[3];
  const float* bhhf = (const float*)d_in[4];
  const float* Wihb = (const float*)d_in[5];
  const float* Whhb = (const float*)d_in[6];
  const float* bihb = (const float*)d_in[7];
  const float* bhhb = (const float*)d_in[8];
  float* out = (float*)d_out;

  // workspace layout
  char* ws = (char*)d_ws;
  _Float16*     x16  = (_Float16*)ws;                          // 32 MiB
  _Float16*     w16  = (_Float16*)(ws + 33554432u);            // 4 MiB
  float*        bias = (float*)   (ws + 33554432u + 4194304u); // 8 KiB
  _Float16*     hbuf = (_Float16*)(ws + 37756928u);            // 256 KiB
  unsigned int* counter = (unsigned int*)(ws + 38019072u);     // 2 per-dir ctrs

  cvt_f32_f16<<<4096, 256, 0, stream>>>(x, x16, (long)M_TOT * I_);
  cvt_f32_f16<<<1024, 256, 0, stream>>>(Wihf, w16, (long)H_ * I_);
  cvt_f32_f16<<<1024, 256, 0, stream>>>(Wihb, w16 + (long)H_ * I_, (long)H_ * I_);
  bias_sum_kernel<<<4, 256, 0, stream>>>(bihf, bhhf, bihb, bhhb, bias, counter);

  dim3 g(H_ / 128, M_TOT / 128, 2);
  gemm_xp_kernel<<<g, 256, 0, stream>>>(x16, w16, bias, out);

  void* args[] = {(void*)&Whhf, (void*)&Whhb, (void*)&out, (void*)&hbuf, (void*)&counter};
  (void)hipLaunchCooperativeKernel((void*)scan_kernel, dim3(64), dim3(256),
                                   args, 0, stream);
}